// Round 1
// 341.142 us; speedup vs baseline: 1.0244x; 1.0244x over previous
//
#include <hip/hip_runtime.h>
#include <math.h>

// ChannelDropout: out[b,c,t] = sig[b,c,t] * kept[b,c] / (1e-8 + proba[b,c])
//   kept[b,c]  = ||pos[b,c] - center|| > 0.2
//   proba[b,c] = mean_i( ||pos[b,c] - mc[i]|| > 0.2 ), i in [0,100)
//
// One block (256 thr) per (b,c) row, T=3000 floats = 750 float4.
// Structure (vs previous version): NO __syncthreads, NO LDS.
//  - Each thread stages its (up to 4) float4 sig loads FIRST -> load latency
//    overlaps the scale computation instead of serializing after it.
//  - Every wave computes the scale redundantly: 100 MC centers are L2-hot
//    (800 B), reduce is a 6-step __shfl_xor butterfly so ALL lanes hold the
//    count -> no broadcast needed.
//  - Nontemporal load/store: both streams are touch-once (419 MB >> L3),
//    avoid L2 allocate churn.
// Memory-bound target: 419 MB @ ~6.3 TB/s ≈ 66 us for the dispatch.

typedef float v4f __attribute__((ext_vector_type(4)));

__global__ __launch_bounds__(256) void channel_dropout_kernel(
    const float* __restrict__ sig,
    const float* __restrict__ pos,
    const float* __restrict__ center,
    const float* __restrict__ mc,
    float* __restrict__ out,
    int T, int NMC)
{
    const int row  = blockIdx.x;           // b*C + c
    const int t    = threadIdx.x;
    const int lane = t & 63;

    const size_t base = (size_t)row * (size_t)T;
    const int n4 = T >> 2;                 // 750 float4 per row (T=3000)
    const v4f* __restrict__ in4  = (const v4f*)(sig + base);
    v4f* __restrict__       out4 = (v4f*)(out + base);

    // ---- stage the streaming loads before the scale is known -------------
    // (row base is 16B-aligned: 3000*4 = 12000 bytes, divisible by 16)
    v4f v[4];
    #pragma unroll
    for (int u = 0; u < 4; ++u) {
        const int i = t + u * 256;
        if (i < n4) v[u] = __builtin_nontemporal_load(in4 + i);
    }

    // ---- per-wave redundant scale computation (no barrier, no LDS) -------
    const float px = pos[2 * row + 0];     // uniform -> scalar loads
    const float py = pos[2 * row + 1];
    const float cx = center[0];
    const float cy = center[1];

    float cnt = 0.0f;
    for (int i = lane; i < NMC; i += 64) { // lanes 0-35 do 2 iters, rest 1
        const float dx = px - mc[2 * i + 0];
        const float dy = py - mc[2 * i + 1];
        cnt += (sqrtf(dx * dx + dy * dy) > 0.2f) ? 1.0f : 0.0f;
    }
    #pragma unroll
    for (int off = 32; off > 0; off >>= 1)  // butterfly: all lanes get sum
        cnt += __shfl_xor(cnt, off, 64);

    const float ddx  = px - cx;
    const float ddy  = py - cy;
    const float kept = (sqrtf(ddx * ddx + ddy * ddy) > 0.2f) ? 1.0f : 0.0f;
    const float scale = kept / (1e-8f + cnt / (float)NMC);

    // ---- scale + store ----------------------------------------------------
    #pragma unroll
    for (int u = 0; u < 4; ++u) {
        const int i = t + u * 256;
        if (i < n4) {
            v4f r = v[u];
            r *= scale;
            __builtin_nontemporal_store(r, out4 + i);
        }
    }
    // general remainder for n4 > 1024 (not hit at T=3000, kept for safety)
    for (int i = t + 1024; i < n4; i += 256) {
        v4f r = __builtin_nontemporal_load(in4 + i);
        r *= scale;
        __builtin_nontemporal_store(r, out4 + i);
    }
    // scalar tail for T % 4 != 0 (not hit for T=3000)
    for (int i = (n4 << 2) + t; i < T; i += 256) {
        out[base + i] = sig[base + i] * scale;
    }
}

extern "C" void kernel_launch(void* const* d_in, const int* in_sizes, int n_in,
                              void* d_out, int out_size, void* d_ws, size_t ws_size,
                              hipStream_t stream) {
    const float* sig    = (const float*)d_in[0];  // (B, C, T) f32
    const float* pos    = (const float*)d_in[1];  // (B, C, 2) f32
    const float* center = (const float*)d_in[2];  // (2,)      f32
    const float* mc     = (const float*)d_in[3];  // (N, 2)    f32
    float* out          = (float*)d_out;          // (B, C, T) f32

    const int rows = in_sizes[1] / 2;             // B*C = 17472
    const int T    = in_sizes[0] / rows;          // 3000
    const int NMC  = in_sizes[3] / 2;             // 100

    channel_dropout_kernel<<<rows, 256, 0, stream>>>(
        sig, pos, center, mc, out, T, NMC);
}